// Round 8
// baseline (1129.488 us; speedup 1.0000x reference)
//
#include <hip/hip_runtime.h>
#include <hip/hip_bf16.h>
#include <cstdint>
#include <type_traits>

typedef unsigned short u16;
typedef __bf16 bf16x8 __attribute__((ext_vector_type(8)));
typedef float f32x4 __attribute__((ext_vector_type(4)));

#define LN_EPS 1e-6f

enum { BIAS_NONE = 0, BIAS_COL = 1, BIAS_ROW = 2 };

__device__ __forceinline__ float b2f(u16 h) {
  union { unsigned u; float f; } v;
  v.u = ((unsigned)h) << 16;
  return v.f;
}
__device__ __forceinline__ u16 f2b(float x) {
  return __bfloat16_as_ushort(__float2bfloat16(x));
}

__device__ __forceinline__ void gld_lds16(const void* g, void* l) {
  __builtin_amdgcn_global_load_lds(
      (const __attribute__((address_space(1))) void*)g,
      (__attribute__((address_space(3))) void*)l, 16, 0, 0);
}

// f32 -> bf16 x8 register conversion staging (verified round 6).
__device__ __forceinline__ void stage8_cvt(const void* src, size_t off,
                                           u16* dst) {
  const float* p = (const float*)src + off;
  const float4 a = *reinterpret_cast<const float4*>(p);
  const float4 b = *reinterpret_cast<const float4*>(p + 4);
  u16 t[8] = {f2b(a.x), f2b(a.y), f2b(a.z), f2b(a.w),
              f2b(b.x), f2b(b.y), f2b(b.z), f2b(b.w)};
  *reinterpret_cast<uint4*>(dst) = *reinterpret_cast<const uint4*>(t);
}

// C[M,N] (ldc stride) = A[M,K] * B[N,K]^T (+bias f32)(+relu). K mult of 32.
// MA/NB clamp staging rows. A_RAW: A is f32, converted in registers; else
// bf16 via async global_load_lds (m97 structure). MFMA core verified round 6.
template <typename OutT, int BIAS, bool RELU, bool A_RAW>
__global__ __launch_bounds__(256, 2) void gemm_mf(
    const void* __restrict__ A, const void* __restrict__ B,
    const float* __restrict__ bias, OutT* __restrict__ C, int M, int N, int K,
    int MA, int NB, int ldc) {
  __shared__ __align__(16) u16 As[128 * 32];
  __shared__ __align__(16) u16 Bs[128 * 32];
  const int tid = threadIdx.x;
  const int lane = tid & 63;
  const int wv = tid >> 6;
  const int wr = (wv >> 1) * 64;
  const int wc = (wv & 1) * 64;
  const int mrow = lane & 15;
  const int quad = lane >> 4;
  const int bm = blockIdx.y * 128;
  const int bn = blockIdx.x * 128;

  f32x4 acc[4][4];
#pragma unroll
  for (int i = 0; i < 4; i++)
#pragma unroll
    for (int j = 0; j < 4; j++) acc[i][j] = f32x4{0.f, 0.f, 0.f, 0.f};

  const int e0 = tid * 8;
  const int r0 = e0 >> 5, kk0 = e0 & 31;
  const int e1 = (256 + tid) * 8;
  const int r1 = e1 >> 5, kk1 = e1 & 31;

  int ra0 = bm + r0; if (ra0 >= MA) ra0 = MA - 1;
  int ra1 = bm + r1; if (ra1 >= MA) ra1 = MA - 1;
  int rb0 = bn + r0; if (rb0 >= NB) rb0 = NB - 1;
  int rb1 = bn + r1; if (rb1 >= NB) rb1 = NB - 1;

  const size_t oa0 = (size_t)ra0 * K + kk0;
  const size_t oa1 = (size_t)ra1 * K + kk1;
  const u16* pb0 = (const u16*)B + (size_t)rb0 * K + kk0;
  const u16* pb1 = (const u16*)B + (size_t)rb1 * K + kk1;

  for (int k0 = 0; k0 < K; k0 += 32) {
    if constexpr (A_RAW) {
      stage8_cvt(A, oa0 + k0, &As[e0]);
      stage8_cvt(A, oa1 + k0, &As[e1]);
    } else {
      gld_lds16((const u16*)A + oa0 + k0, &As[e0]);
      gld_lds16((const u16*)A + oa1 + k0, &As[e1]);
    }
    gld_lds16(pb0 + k0, &Bs[e0]);
    gld_lds16(pb1 + k0, &Bs[e1]);
    __syncthreads();
    bf16x8 af[4], bfm[4];
#pragma unroll
    for (int i = 0; i < 4; i++) {
      af[i] = *reinterpret_cast<const bf16x8*>(
          &As[(wr + i * 16 + mrow) * 32 + quad * 8]);
      bfm[i] = *reinterpret_cast<const bf16x8*>(
          &Bs[(wc + i * 16 + mrow) * 32 + quad * 8]);
    }
#pragma unroll
    for (int i = 0; i < 4; i++)
#pragma unroll
      for (int j = 0; j < 4; j++)
        acc[i][j] = __builtin_amdgcn_mfma_f32_16x16x32_bf16(af[i], bfm[j],
                                                            acc[i][j], 0, 0, 0);
    __syncthreads();
  }

#pragma unroll
  for (int i = 0; i < 4; i++) {
#pragma unroll
    for (int j = 0; j < 4; j++) {
#pragma unroll
      for (int r = 0; r < 4; r++) {
        const int gr = bm + wr + i * 16 + quad * 4 + r;
        const int gc = bn + wc + j * 16 + mrow;
        if (gr < M && gc < N) {
          float v = acc[i][j][r];
          if (BIAS == BIAS_COL) v += bias[gc];
          if (BIAS == BIAS_ROW) v += bias[gr];
          if (RELU) v = fmaxf(v, 0.f);
          if constexpr (std::is_same<OutT, float>::value)
            C[(size_t)gr * ldc + gc] = v;
          else
            C[(size_t)gr * ldc + gc] = f2b(v);
        }
      }
    }
  }
}

// f32 -> bf16 bulk conversion, 8 elements/thread. n8 = n/8.
__global__ __launch_bounds__(256) void cvt_k(const float* __restrict__ src,
                                             u16* __restrict__ dst, int n8) {
  const int i = blockIdx.x * 256 + threadIdx.x;
  if (i >= n8) return;
  stage8_cvt(src, (size_t)i * 8, dst + (size_t)i * 8);
}

// In-place softmax over Sp[row, 0..224) bf16: p = softmax((s + score)/8)
// over cols < 196; cols 196..223 set to 0. One wave per row.
__global__ __launch_bounds__(256) void softmax_k(
    u16* __restrict__ Sp, const float* __restrict__ score) {
  const int row = blockIdx.x * 4 + (threadIdx.x >> 6);
  const int lane = threadIdx.x & 63;
  float x[4];
  float mx = -1e30f;
#pragma unroll
  for (int t = 0; t < 4; t++) {
    const int s = lane + 64 * t;
    float v = -1e30f;
    if (s < 196)
      v = (b2f(Sp[(size_t)row * 224 + s]) + score[(size_t)row * 196 + s]) *
          0.125f;
    x[t] = v;
    mx = fmaxf(mx, v);
  }
#pragma unroll
  for (int off = 32; off > 0; off >>= 1) mx = fmaxf(mx, __shfl_xor(mx, off));
  float sum = 0.f;
#pragma unroll
  for (int t = 0; t < 4; t++) {
    const int s = lane + 64 * t;
    const float e = (s < 196) ? expf(x[t] - mx) : 0.f;
    x[t] = e;
    sum += e;
  }
#pragma unroll
  for (int off = 32; off > 0; off >>= 1) sum += __shfl_xor(sum, off);
  const float inv = 1.f / sum;
#pragma unroll
  for (int t = 0; t < 4; t++) {
    const int s = lane + 64 * t;
    if (s < 224) Sp[(size_t)row * 224 + s] = f2b((s < 196) ? x[t] * inv : 0.f);
  }
}

// t = LN(X(f32) + Y(bf16))*g + be over D=1024;
// pooled[row, colbase+i](bf16) = max(t[2i], t[2i+1]).
__global__ __launch_bounds__(256) void ln_pool_k(
    const float* __restrict__ X, const u16* __restrict__ Y,
    const float* __restrict__ g, const float* __restrict__ be,
    u16* __restrict__ pooled, int colbase) {
  const int row = blockIdx.x;
  const int tid = threadIdx.x;
  const int lane = tid & 63;
  const int wv = tid >> 6;
  __shared__ float red[4];
  float v[4];
  float s = 0.f;
  const size_t base = (size_t)row * 1024 + tid * 4;
#pragma unroll
  for (int j = 0; j < 4; j++) {
    const float a = X[base + j] + b2f(Y[base + j]);
    v[j] = a;
    s += a;
  }
#pragma unroll
  for (int off = 32; off > 0; off >>= 1) s += __shfl_xor(s, off);
  if (lane == 0) red[wv] = s;
  __syncthreads();
  const float mu = (red[0] + red[1] + red[2] + red[3]) * (1.f / 1024.f);
  __syncthreads();
  float var = 0.f;
#pragma unroll
  for (int j = 0; j < 4; j++) {
    const float d = v[j] - mu;
    var += d * d;
  }
#pragma unroll
  for (int off = 32; off > 0; off >>= 1) var += __shfl_xor(var, off);
  if (lane == 0) red[wv] = var;
  __syncthreads();
  var = (red[0] + red[1] + red[2] + red[3]) * (1.f / 1024.f);
  const float rs = rsqrtf(var + LN_EPS);
  float n[4];
#pragma unroll
  for (int j = 0; j < 4; j++)
    n[j] = (v[j] - mu) * rs * g[tid * 4 + j] + be[tid * 4 + j];
  const size_t pb = (size_t)row * 1024 + colbase + tid * 2;
  pooled[pb] = f2b(fmaxf(n[0], n[1]));
  pooled[pb + 1] = f2b(fmaxf(n[2], n[3]));
}

// out(f32) = LN(X(bf16) + Y(bf16))*g + be over D=1024.
__global__ __launch_bounds__(256) void ln_out_k(
    const u16* __restrict__ X, const u16* __restrict__ Y,
    const float* __restrict__ g, const float* __restrict__ be,
    float* __restrict__ out) {
  const int row = blockIdx.x;
  const int tid = threadIdx.x;
  const int lane = tid & 63;
  const int wv = tid >> 6;
  __shared__ float red[4];
  float v[4];
  float s = 0.f;
  const size_t base = (size_t)row * 1024 + tid * 4;
#pragma unroll
  for (int j = 0; j < 4; j++) {
    const float a = b2f(X[base + j]) + b2f(Y[base + j]);
    v[j] = a;
    s += a;
  }
#pragma unroll
  for (int off = 32; off > 0; off >>= 1) s += __shfl_xor(s, off);
  if (lane == 0) red[wv] = s;
  __syncthreads();
  const float mu = (red[0] + red[1] + red[2] + red[3]) * (1.f / 1024.f);
  __syncthreads();
  float var = 0.f;
#pragma unroll
  for (int j = 0; j < 4; j++) {
    const float d = v[j] - mu;
    var += d * d;
  }
#pragma unroll
  for (int off = 32; off > 0; off >>= 1) var += __shfl_xor(var, off);
  if (lane == 0) red[wv] = var;
  __syncthreads();
  var = (red[0] + red[1] + red[2] + red[3]) * (1.f / 1024.f);
  const float rs = rsqrtf(var + LN_EPS);
#pragma unroll
  for (int j = 0; j < 4; j++)
    out[base + j] = (v[j] - mu) * rs * g[tid * 4 + j] + be[tid * 4 + j];
}

extern "C" void kernel_launch(void* const* d_in, const int* in_sizes, int n_in,
                              void* d_out, int out_size, void* d_ws,
                              size_t ws_size, hipStream_t stream) {
  const size_t MB = 1ull << 20;
  if (ws_size < 61 * MB) return;  // proven >= 61 MiB (round 6 ran)

  const float* text1 = (const float*)d_in[0];
  const float* vis1 = (const float*)d_in[1];
  const float* sc1 = (const float*)d_in[2];
  const float* text2 = (const float*)d_in[3];
  const float* vis2 = (const float*)d_in[4];
  const float* sc2 = (const float*)d_in[5];
  const float* Wq = (const float*)d_in[6];
  const float* bq = (const float*)d_in[7];
  const float* Wk = (const float*)d_in[8];
  const float* bk = (const float*)d_in[9];
  const float* Wv = (const float*)d_in[10];
  const float* bv = (const float*)d_in[11];
  const float* Wo = (const float*)d_in[12];
  const float* bo = (const float*)d_in[13];
  const float* W1 = (const float*)d_in[14];
  const float* b1 = (const float*)d_in[15];
  const float* W2 = (const float*)d_in[16];
  const float* b2 = (const float*)d_in[17];
  const float* g1 = (const float*)d_in[18];
  const float* be1 = (const float*)d_in[19];
  const float* g2 = (const float*)d_in[20];
  const float* be2 = (const float*)d_in[21];

  const int M = 8192, D = 1024, Sv = 196, SvP = 224, DFF = 4096;
  char* w = (char*)d_ws;
  // ws layout (55 MiB peak):
  //  [0,16)   pooled bf16 [8192,1024] (persists)
  //  Phase A: [16,18) Wqb  [18,20) Wkb  [20,22) Wvb  [22,24) Wob
  //           [24,25) Km bf16 [196,1024]   [25,26) Vt bf16 [1024,224]
  //           [26,42) Q bf16 [8192,1024] (AV reuses after S-GEMM)
  //           [42,46) Sp bf16 [8192,224] (in-place softmax -> P)
  //           [46,54) Yc bf16 [4096,1024] (2 chunks)
  //           [54,55) visb bf16 [196,1024]
  //  Phase B: [16,24) W1b  [24,32) W2b  [32,48) H bf16 [2048,4096]
  //           [48,52) F bf16 [2048,1024]
  u16* pooled = (u16*)(w + 0 * MB);
  u16* Wqb = (u16*)(w + 16 * MB);
  u16* Wkb = (u16*)(w + 18 * MB);
  u16* Wvb = (u16*)(w + 20 * MB);
  u16* Wob = (u16*)(w + 22 * MB);
  u16* Km = (u16*)(w + 24 * MB);
  u16* Vt = (u16*)(w + 25 * MB);
  u16* Q = (u16*)(w + 26 * MB);
  u16* Sp = (u16*)(w + 42 * MB);
  u16* Yc = (u16*)(w + 46 * MB);
  u16* visb = (u16*)(w + 54 * MB);
  u16* AV = Q;  // Q dead after S-GEMM
  u16* W1b = (u16*)(w + 16 * MB);
  u16* W2b = (u16*)(w + 24 * MB);
  u16* H = (u16*)(w + 32 * MB);
  u16* F = (u16*)(w + 48 * MB);

  auto grid = [](int m, int n) {
    return dim3((unsigned)((n + 127) / 128), (unsigned)((m + 127) / 128));
  };
  auto cgrid = [](int n) { return dim3((unsigned)((n / 8 + 255) / 256)); };

  // Convert attention weights to bf16 once.
  cvt_k<<<cgrid(D * D), 256, 0, stream>>>(Wq, Wqb, D * D / 8);
  cvt_k<<<cgrid(D * D), 256, 0, stream>>>(Wk, Wkb, D * D / 8);
  cvt_k<<<cgrid(D * D), 256, 0, stream>>>(Wv, Wvb, D * D / 8);
  cvt_k<<<cgrid(D * D), 256, 0, stream>>>(Wo, Wob, D * D / 8);

  for (int br = 0; br < 2; ++br) {
    const float* text = br ? text2 : text1;
    const float* vis = br ? vis2 : vis1;
    const float* sc = br ? sc2 : sc1;

    cvt_k<<<cgrid(Sv * D), 256, 0, stream>>>(vis, visb, Sv * D / 8);
    // Km = vis @ Wk^T + bk   [196,1024]
    gemm_mf<u16, BIAS_COL, false, false><<<grid(Sv, D), 256, 0, stream>>>(
        visb, Wkb, bk, Km, Sv, D, D, Sv, D, D);
    // Vt[d,s] = Wv[d]·vis[s] + bv[d]   [1024,224] (NB=196 clamp)
    gemm_mf<u16, BIAS_ROW, false, false><<<grid(D, SvP), 256, 0, stream>>>(
        Wvb, visb, bv, Vt, D, SvP, D, D, Sv, SvP);
    // Q = text @ Wq^T + bq   [8192,1024]  (A raw f32)
    gemm_mf<u16, BIAS_COL, false, true><<<grid(M, D), 256, 0, stream>>>(
        text, Wqb, bq, Q, M, D, D, M, D, D);
    // Sp = Q @ Km^T   [8192, ldc=224] bf16, store cols < 196
    gemm_mf<u16, BIAS_NONE, false, false><<<grid(M, SvP), 256, 0, stream>>>(
        Q, Km, nullptr, Sp, M, Sv, D, M, Sv, SvP);
    // Sp <- softmax((Sp + score)/8), pad zeros
    softmax_k<<<dim3(M / 4), 256, 0, stream>>>(Sp, sc);
    // AV = Sp @ Vt^T   [8192,1024], K=224 (into dead Q slot)
    gemm_mf<u16, BIAS_NONE, false, false><<<grid(M, D), 256, 0, stream>>>(
        Sp, Vt, nullptr, AV, M, D, SvP, M, D, D);
    // O-proj + residual-LN-pool in 2 chunks of 4096 rows
    for (int c = 0; c < 2; ++c) {
      const int r0 = c * 4096, rows = 4096;
      gemm_mf<u16, BIAS_COL, false, false><<<grid(rows, D), 256, 0, stream>>>(
          AV + (size_t)r0 * D, Wob, bo, Yc, rows, D, D, rows, D, D);
      ln_pool_k<<<dim3(rows), 256, 0, stream>>>(
          text + (size_t)r0 * D, Yc, g1, be1, pooled + (size_t)r0 * D,
          br * 512);
    }
  }

  // FFN weights to bf16 (phase-A slots dead).
  cvt_k<<<cgrid(DFF * D), 256, 0, stream>>>(W1, W1b, DFF * D / 8);
  cvt_k<<<cgrid(DFF * D), 256, 0, stream>>>(W2, W2b, DFF * D / 8);

  // FFN in 4 row-chunks of 2048.
  for (int c = 0; c < 4; ++c) {
    const int r0 = c * 2048, rows = 2048;
    gemm_mf<u16, BIAS_COL, true, false><<<grid(rows, DFF), 256, 0, stream>>>(
        pooled + (size_t)r0 * D, W1b, b1, H, rows, DFF, D, rows, DFF, DFF);
    gemm_mf<u16, BIAS_COL, false, false><<<grid(rows, D), 256, 0, stream>>>(
        H, W2b, b2, F, rows, D, DFF, rows, D, D);
    ln_out_k<<<dim3(rows), 256, 0, stream>>>(
        pooled + (size_t)r0 * D, F, g2, be2, (float*)d_out + (size_t)r0 * D);
  }
}

// Round 9
// 893.307 us; speedup vs baseline: 1.2644x; 1.2644x over previous
//
#include <hip/hip_runtime.h>
#include <hip/hip_bf16.h>
#include <cstdint>
#include <type_traits>

typedef unsigned short u16;
typedef __bf16 bf16x8 __attribute__((ext_vector_type(8)));
typedef float f32x4 __attribute__((ext_vector_type(4)));

#define LN_EPS 1e-6f

enum { BIAS_NONE = 0, BIAS_COL = 1, BIAS_ROW = 2 };

__device__ __forceinline__ float b2f(u16 h) {
  union { unsigned u; float f; } v;
  v.u = ((unsigned)h) << 16;
  return v.f;
}
__device__ __forceinline__ u16 f2b(float x) {
  return __bfloat16_as_ushort(__float2bfloat16(x));
}

__device__ __forceinline__ void gld_lds16(const void* g, void* l) {
  __builtin_amdgcn_global_load_lds(
      (const __attribute__((address_space(1))) void*)g,
      (__attribute__((address_space(3))) void*)l, 16, 0, 0);
}

// f32 -> bf16 x8 register conversion staging (verified round 6).
__device__ __forceinline__ void stage8_cvt(const void* src, size_t off,
                                           u16* dst) {
  const float* p = (const float*)src + off;
  const float4 a = *reinterpret_cast<const float4*>(p);
  const float4 b = *reinterpret_cast<const float4*>(p + 4);
  u16 t[8] = {f2b(a.x), f2b(a.y), f2b(a.z), f2b(a.w),
              f2b(b.x), f2b(b.y), f2b(b.z), f2b(b.w)};
  *reinterpret_cast<uint4*>(dst) = *reinterpret_cast<const uint4*>(t);
}

// C[M,N] (ldc) = A[M,K] * B[N,K]^T (+bias f32)(+relu). K mult of 32.
// MA/NB clamp staging rows. A_RAW/B_RAW: operand is f32, converted in
// registers; else bf16 via async global_load_lds.
// TN=128: 4 waves as 2x2 of 64x64 (16 KB LDS). TN=64: 4 waves as 4x1 of
// 32x64 (12 KB LDS, ~2x grid concurrency). MFMA core verified round 6.
template <typename OutT, int BIAS, bool RELU, bool A_RAW, bool B_RAW, int TN>
__global__ __launch_bounds__(256, 2) void gemm_mf(
    const void* __restrict__ A, const void* __restrict__ B,
    const float* __restrict__ bias, OutT* __restrict__ C, int M, int N, int K,
    int MA, int NB, int ldc) {
  constexpr int AI = (TN == 128) ? 4 : 2;
  __shared__ __align__(16) u16 As[128 * 32];
  __shared__ __align__(16) u16 Bs[TN * 32];
  const int tid = threadIdx.x;
  const int lane = tid & 63;
  const int wv = tid >> 6;
  const int wr = (TN == 128) ? (wv >> 1) * 64 : wv * 32;
  const int wc = (TN == 128) ? (wv & 1) * 64 : 0;
  const int mrow = lane & 15;
  const int quad = lane >> 4;
  const int bm = blockIdx.y * 128;
  const int bn = blockIdx.x * TN;

  f32x4 acc[AI][4];
#pragma unroll
  for (int i = 0; i < AI; i++)
#pragma unroll
    for (int j = 0; j < 4; j++) acc[i][j] = f32x4{0.f, 0.f, 0.f, 0.f};

  // Staging: tile elems = rows*32; 256 threads x 8 bf16 (16B) per slot.
  const int e0 = tid * 8;
  const int r0 = e0 >> 5, kk = e0 & 31;

  int ra0 = bm + r0;        if (ra0 >= MA) ra0 = MA - 1;
  int ra1 = bm + r0 + 64;   if (ra1 >= MA) ra1 = MA - 1;
  int rb0 = bn + r0;        if (rb0 >= NB) rb0 = NB - 1;
  int rb1 = bn + r0 + 64;   if (rb1 >= NB) rb1 = NB - 1;  // TN==128 only

  const size_t oa0 = (size_t)ra0 * K + kk;
  const size_t oa1 = (size_t)ra1 * K + kk;
  const size_t ob0 = (size_t)rb0 * K + kk;
  const size_t ob1 = (size_t)rb1 * K + kk;

  for (int k0 = 0; k0 < K; k0 += 32) {
    if constexpr (A_RAW) {
      stage8_cvt(A, oa0 + k0, &As[e0]);
      stage8_cvt(A, oa1 + k0, &As[e0 + 2048]);
    } else {
      gld_lds16((const u16*)A + oa0 + k0, &As[e0]);
      gld_lds16((const u16*)A + oa1 + k0, &As[e0 + 2048]);
    }
    if constexpr (B_RAW) {
      stage8_cvt(B, ob0 + k0, &Bs[e0]);
      if constexpr (TN == 128) stage8_cvt(B, ob1 + k0, &Bs[e0 + 2048]);
    } else {
      gld_lds16((const u16*)B + ob0 + k0, &Bs[e0]);
      if constexpr (TN == 128) gld_lds16((const u16*)B + ob1 + k0,
                                         &Bs[e0 + 2048]);
    }
    __syncthreads();
    bf16x8 af[AI], bfm[4];
#pragma unroll
    for (int i = 0; i < AI; i++)
      af[i] = *reinterpret_cast<const bf16x8*>(
          &As[(wr + i * 16 + mrow) * 32 + quad * 8]);
#pragma unroll
    for (int j = 0; j < 4; j++)
      bfm[j] = *reinterpret_cast<const bf16x8*>(
          &Bs[(wc + j * 16 + mrow) * 32 + quad * 8]);
#pragma unroll
    for (int i = 0; i < AI; i++)
#pragma unroll
      for (int j = 0; j < 4; j++)
        acc[i][j] = __builtin_amdgcn_mfma_f32_16x16x32_bf16(af[i], bfm[j],
                                                            acc[i][j], 0, 0, 0);
    __syncthreads();
  }

#pragma unroll
  for (int i = 0; i < AI; i++) {
#pragma unroll
    for (int j = 0; j < 4; j++) {
#pragma unroll
      for (int r = 0; r < 4; r++) {
        const int gr = bm + wr + i * 16 + quad * 4 + r;
        const int gc = bn + wc + j * 16 + mrow;
        if (gr < M && gc < N) {
          float v = acc[i][j][r];
          if (BIAS == BIAS_COL) v += bias[gc];
          if (BIAS == BIAS_ROW) v += bias[gr];
          if (RELU) v = fmaxf(v, 0.f);
          if constexpr (std::is_same<OutT, float>::value)
            C[(size_t)gr * ldc + gc] = v;
          else
            C[(size_t)gr * ldc + gc] = f2b(v);
        }
      }
    }
  }
}

// f32 -> bf16 bulk conversion, 8 elements/thread. n8 = n/8.
__global__ __launch_bounds__(256) void cvt_k(const float* __restrict__ src,
                                             u16* __restrict__ dst, int n8) {
  const int i = blockIdx.x * 256 + threadIdx.x;
  if (i >= n8) return;
  stage8_cvt(src, (size_t)i * 8, dst + (size_t)i * 8);
}

// In-place softmax over Sp[row, 0..224) bf16: p = softmax((s + score)/8)
// over cols < 196; cols 196..223 set to 0. One wave per row.
__global__ __launch_bounds__(256) void softmax_k(
    u16* __restrict__ Sp, const float* __restrict__ score) {
  const int row = blockIdx.x * 4 + (threadIdx.x >> 6);
  const int lane = threadIdx.x & 63;
  float x[4];
  float mx = -1e30f;
#pragma unroll
  for (int t = 0; t < 4; t++) {
    const int s = lane + 64 * t;
    float v = -1e30f;
    if (s < 196)
      v = (b2f(Sp[(size_t)row * 224 + s]) + score[(size_t)row * 196 + s]) *
          0.125f;
    x[t] = v;
    mx = fmaxf(mx, v);
  }
#pragma unroll
  for (int off = 32; off > 0; off >>= 1) mx = fmaxf(mx, __shfl_xor(mx, off));
  float sum = 0.f;
#pragma unroll
  for (int t = 0; t < 4; t++) {
    const int s = lane + 64 * t;
    const float e = (s < 196) ? expf(x[t] - mx) : 0.f;
    x[t] = e;
    sum += e;
  }
#pragma unroll
  for (int off = 32; off > 0; off >>= 1) sum += __shfl_xor(sum, off);
  const float inv = 1.f / sum;
#pragma unroll
  for (int t = 0; t < 4; t++) {
    const int s = lane + 64 * t;
    if (s < 224) Sp[(size_t)row * 224 + s] = f2b((s < 196) ? x[t] * inv : 0.f);
  }
}

// t = LN(X(f32) + Y(bf16))*g + be over D=1024;
// pooled[row, colbase+i](bf16) = max(t[2i], t[2i+1]).
__global__ __launch_bounds__(256) void ln_pool_k(
    const float* __restrict__ X, const u16* __restrict__ Y,
    const float* __restrict__ g, const float* __restrict__ be,
    u16* __restrict__ pooled, int colbase) {
  const int row = blockIdx.x;
  const int tid = threadIdx.x;
  const int lane = tid & 63;
  const int wv = tid >> 6;
  __shared__ float red[4];
  float v[4];
  float s = 0.f;
  const size_t base = (size_t)row * 1024 + tid * 4;
#pragma unroll
  for (int j = 0; j < 4; j++) {
    const float a = X[base + j] + b2f(Y[base + j]);
    v[j] = a;
    s += a;
  }
#pragma unroll
  for (int off = 32; off > 0; off >>= 1) s += __shfl_xor(s, off);
  if (lane == 0) red[wv] = s;
  __syncthreads();
  const float mu = (red[0] + red[1] + red[2] + red[3]) * (1.f / 1024.f);
  __syncthreads();
  float var = 0.f;
#pragma unroll
  for (int j = 0; j < 4; j++) {
    const float d = v[j] - mu;
    var += d * d;
  }
#pragma unroll
  for (int off = 32; off > 0; off >>= 1) var += __shfl_xor(var, off);
  if (lane == 0) red[wv] = var;
  __syncthreads();
  var = (red[0] + red[1] + red[2] + red[3]) * (1.f / 1024.f);
  const float rs = rsqrtf(var + LN_EPS);
  float n[4];
#pragma unroll
  for (int j = 0; j < 4; j++)
    n[j] = (v[j] - mu) * rs * g[tid * 4 + j] + be[tid * 4 + j];
  const size_t pb = (size_t)row * 1024 + colbase + tid * 2;
  pooled[pb] = f2b(fmaxf(n[0], n[1]));
  pooled[pb + 1] = f2b(fmaxf(n[2], n[3]));
}

// out(f32) = LN(X(bf16) + Y(bf16))*g + be over D=1024.
__global__ __launch_bounds__(256) void ln_out_k(
    const u16* __restrict__ X, const u16* __restrict__ Y,
    const float* __restrict__ g, const float* __restrict__ be,
    float* __restrict__ out) {
  const int row = blockIdx.x;
  const int tid = threadIdx.x;
  const int lane = tid & 63;
  const int wv = tid >> 6;
  __shared__ float red[4];
  float v[4];
  float s = 0.f;
  const size_t base = (size_t)row * 1024 + tid * 4;
#pragma unroll
  for (int j = 0; j < 4; j++) {
    const float a = b2f(X[base + j]) + b2f(Y[base + j]);
    v[j] = a;
    s += a;
  }
#pragma unroll
  for (int off = 32; off > 0; off >>= 1) s += __shfl_xor(s, off);
  if (lane == 0) red[wv] = s;
  __syncthreads();
  const float mu = (red[0] + red[1] + red[2] + red[3]) * (1.f / 1024.f);
  __syncthreads();
  float var = 0.f;
#pragma unroll
  for (int j = 0; j < 4; j++) {
    const float d = v[j] - mu;
    var += d * d;
  }
#pragma unroll
  for (int off = 32; off > 0; off >>= 1) var += __shfl_xor(var, off);
  if (lane == 0) red[wv] = var;
  __syncthreads();
  var = (red[0] + red[1] + red[2] + red[3]) * (1.f / 1024.f);
  const float rs = rsqrtf(var + LN_EPS);
#pragma unroll
  for (int j = 0; j < 4; j++)
    out[base + j] = (v[j] - mu) * rs * g[tid * 4 + j] + be[tid * 4 + j];
}

extern "C" void kernel_launch(void* const* d_in, const int* in_sizes, int n_in,
                              void* d_out, int out_size, void* d_ws,
                              size_t ws_size, hipStream_t stream) {
  const size_t MB = 1ull << 20;
  if (ws_size < 61 * MB) return;  // proven >= 61 MiB (round 6 ran)

  const float* text1 = (const float*)d_in[0];
  const float* vis1 = (const float*)d_in[1];
  const float* sc1 = (const float*)d_in[2];
  const float* text2 = (const float*)d_in[3];
  const float* vis2 = (const float*)d_in[4];
  const float* sc2 = (const float*)d_in[5];
  const float* Wq = (const float*)d_in[6];
  const float* bq = (const float*)d_in[7];
  const float* Wk = (const float*)d_in[8];
  const float* bk = (const float*)d_in[9];
  const float* Wv = (const float*)d_in[10];
  const float* bv = (const float*)d_in[11];
  const float* Wo = (const float*)d_in[12];
  const float* bo = (const float*)d_in[13];
  const float* W1 = (const float*)d_in[14];
  const float* b1 = (const float*)d_in[15];
  const float* W2 = (const float*)d_in[16];
  const float* b2 = (const float*)d_in[17];
  const float* g1 = (const float*)d_in[18];
  const float* be1 = (const float*)d_in[19];
  const float* g2 = (const float*)d_in[20];
  const float* be2 = (const float*)d_in[21];

  const int M = 8192, D = 1024, Sv = 196, SvP = 224, DFF = 4096;
  char* w = (char*)d_ws;
  // ws layout (<= 56 MiB peak, proven budget 61):
  //  [0,16)   pooled bf16 [8192,1024] (persists)
  //  Phase A: [16,24) Wqb/Wkb/Wvb/Wob (2 MB each)
  //           [24,24.5) visb  [24.5,25) Km  [25,25.5) Vt
  //           [26,42) Q bf16 [8192,1024] (AV reuses after S-GEMM)
  //           [42,45.5) Sp bf16 [8192,224]
  //           [46,54) Yc bf16 [4096,1024]
  //  Phase B: [16,48) H bf16 [4096,4096]   [48,56) F bf16 [4096,1024]
  //           (FFN weights staged raw f32 -> no W1b/W2b buffers)
  u16* pooled = (u16*)(w + 0 * MB);
  u16* Wqb = (u16*)(w + 16 * MB);
  u16* Wkb = (u16*)(w + 18 * MB);
  u16* Wvb = (u16*)(w + 20 * MB);
  u16* Wob = (u16*)(w + 22 * MB);
  u16* visb = (u16*)(w + 24 * MB);
  u16* Km = (u16*)(w + 24 * MB + 512 * 1024);
  u16* Vt = (u16*)(w + 25 * MB);
  u16* Q = (u16*)(w + 26 * MB);
  u16* Sp = (u16*)(w + 42 * MB);
  u16* Yc = (u16*)(w + 46 * MB);
  u16* AV = Q;  // Q dead after S-GEMM
  u16* H = (u16*)(w + 16 * MB);
  u16* F = (u16*)(w + 48 * MB);

  auto grid = [](int m, int n, int tn) {
    return dim3((unsigned)((n + tn - 1) / tn), (unsigned)((m + 127) / 128));
  };
  auto cgrid = [](int n) { return dim3((unsigned)((n / 8 + 255) / 256)); };

  // Convert attention weights to bf16 once.
  cvt_k<<<cgrid(D * D), 256, 0, stream>>>(Wq, Wqb, D * D / 8);
  cvt_k<<<cgrid(D * D), 256, 0, stream>>>(Wk, Wkb, D * D / 8);
  cvt_k<<<cgrid(D * D), 256, 0, stream>>>(Wv, Wvb, D * D / 8);
  cvt_k<<<cgrid(D * D), 256, 0, stream>>>(Wo, Wob, D * D / 8);

  for (int br = 0; br < 2; ++br) {
    const float* text = br ? text2 : text1;
    const float* vis = br ? vis2 : vis1;
    const float* sc = br ? sc2 : sc1;

    cvt_k<<<cgrid(Sv * D), 256, 0, stream>>>(vis, visb, Sv * D / 8);
    // Km = vis @ Wk^T + bk   [196,1024]
    gemm_mf<u16, BIAS_COL, false, false, false, 64>
        <<<grid(Sv, D, 64), 256, 0, stream>>>(visb, Wkb, bk, Km, Sv, D, D, Sv,
                                              D, D);
    // Vt[d,s] = Wv[d]·vis[s] + bv[d]   [1024,224] (NB=196 clamp)
    gemm_mf<u16, BIAS_ROW, false, false, false, 64>
        <<<grid(D, SvP, 64), 256, 0, stream>>>(Wvb, visb, bv, Vt, D, SvP, D, D,
                                               Sv, SvP);
    // Q = text @ Wq^T + bq   [8192,1024]  (A raw f32) -- 1024 blocks
    gemm_mf<u16, BIAS_COL, false, true, false, 64>
        <<<grid(M, D, 64), 256, 0, stream>>>(text, Wqb, bq, Q, M, D, D, M, D,
                                             D);
    // Sp = Q @ Km^T   [8192, ldc=224] bf16, store cols < 196
    gemm_mf<u16, BIAS_NONE, false, false, false, 64>
        <<<grid(M, Sv, 64), 256, 0, stream>>>(Q, Km, nullptr, Sp, M, Sv, D, M,
                                              Sv, SvP);
    // Sp <- softmax((Sp + score)/8), pad zeros
    softmax_k<<<dim3(M / 4), 256, 0, stream>>>(Sp, sc);
    // AV = Sp @ Vt^T   [8192,1024], K=224 (into dead Q slot) -- 1024 blocks
    gemm_mf<u16, BIAS_NONE, false, false, false, 64>
        <<<grid(M, D, 64), 256, 0, stream>>>(Sp, Vt, nullptr, AV, M, D, SvP, M,
                                             D, D);
    // O-proj + residual-LN-pool in 2 chunks of 4096 rows
    for (int c = 0; c < 2; ++c) {
      const int r0 = c * 4096, rows = 4096;
      gemm_mf<u16, BIAS_COL, false, false, false, 64>
          <<<grid(rows, D, 64), 256, 0, stream>>>(AV + (size_t)r0 * D, Wob, bo,
                                                  Yc, rows, D, D, rows, D, D);
      ln_pool_k<<<dim3(rows), 256, 0, stream>>>(
          text + (size_t)r0 * D, Yc, g1, be1, pooled + (size_t)r0 * D,
          br * 512);
    }
  }

  // FFN in 2 row-chunks of 4096; weights staged raw f32 (saves ws).
  for (int c = 0; c < 2; ++c) {
    const int r0 = c * 4096, rows = 4096;
    // H = relu(pooled_c @ W1^T + b1)  -- grid (32,32) = 1024 blocks
    gemm_mf<u16, BIAS_COL, true, false, true, 128>
        <<<grid(rows, DFF, 128), 256, 0, stream>>>(pooled + (size_t)r0 * D, W1,
                                                   b1, H, rows, DFF, D, rows,
                                                   DFF, DFF);
    // F = H @ W2^T + b2  -- grid (16,32) = 512 blocks
    gemm_mf<u16, BIAS_COL, false, false, true, 64>
        <<<grid(rows, D, 64), 256, 0, stream>>>(H, W2, b2, F, rows, D, DFF,
                                                rows, D, D);
    // out_c = LN(pooled_c + F)  f32
    ln_out_k<<<dim3(rows), 256, 0, stream>>>(
        pooled + (size_t)r0 * D, F, g2, be2, (float*)d_out + (size_t)r0 * D);
  }
}